// Round 3
// baseline (72.540 us; speedup 1.0000x reference)
//
#include <hip/hip_runtime.h>
#include <hip/hip_bf16.h>

// Problem constants (from reference): B=32, T=256, D=128, tau=0.02
#define B_SZ 32
#define T_SZ 256
#define D_SZ 128
#define TAU_INV 50.0f

typedef __bf16 bf16x8 __attribute__((ext_vector_type(8)));
typedef float f32x4 __attribute__((ext_vector_type(4)));

// masks arrive either as int32 (harness "integer -> int*") or raw bool bytes.
// Element [0][0] is always true (q_len,p_len >= 64), so int32 layout reads 1,
// byte layout reads 0x01010101. Deterministic (input-only) detection.
__device__ __forceinline__ bool mask_is_byte(const void* m) {
    return ((const int*)m)[0] != 1;
}
__device__ __forceinline__ int mget(const void* m, int idx, bool isb) {
    return isb ? (((const unsigned char*)m)[idx] != 0) : (((const int*)m)[idx] != 0);
}

// 8 fp32 -> bf16x8 (compiler emits v_cvt_pk_bf16_f32 pairs; m240: don't hand-asm)
__device__ __forceinline__ bf16x8 cvt8(float4 a, float4 b) {
    union { bf16x8 v; __hip_bfloat16 h[8]; } u;
    u.h[0] = __float2bfloat16(a.x); u.h[1] = __float2bfloat16(a.y);
    u.h[2] = __float2bfloat16(a.z); u.h[3] = __float2bfloat16(a.w);
    u.h[4] = __float2bfloat16(b.x); u.h[5] = __float2bfloat16(b.y);
    u.h[6] = __float2bfloat16(b.z); u.h[7] = __float2bfloat16(b.w);
    return u.v;
}

// One block per (b,c) pair. Converts fp32->bf16 inline, MFMA late-interaction
// score -> sraw[b*32+c]. Last block (fenced atomic counter) computes the
// dense sim + all losses, reusing the LDS buffer.
__global__ __launch_bounds__(256) void fused_all(
    const float* __restrict__ qs,  const float* __restrict__ ps,
    const float* __restrict__ qm3, const float* __restrict__ pm3,
    const void* __restrict__ qmask, const void* __restrict__ pmask,
    float* __restrict__ sraw, unsigned int* __restrict__ counter,
    float* __restrict__ out)
{
    __shared__ __align__(16) unsigned char Plds[T_SZ * D_SZ * 2]; // 64 KB, XOR-swizzled
    __shared__ float madd[T_SZ];  // 0 or -1e30 per p token
    __shared__ float qmul[T_SZ];  // 1 or 0 per q token
    __shared__ float wsum[4];
    __shared__ int lastflag;

    const int tid = threadIdx.x;
    const int l   = tid & 63;
    const int w   = tid >> 6;       // wave 0..3
    const int bid = blockIdx.x;
    const int b   = bid >> 5;
    const int c   = bid & 31;
    const int lr  = l & 15;         // fragment row/col lane
    const int lg  = l >> 4;         // k-group / row-group

    const bool isb = mask_is_byte(qmask);
    const float* Qb32 = qm3 + b * (T_SZ * D_SZ);
    const float4* Pc4 = (const float4*)(pm3 + c * (T_SZ * D_SZ));

    // stage P tile: fp32 global -> bf16 LDS, chunk swizzle chunk' = chunk^(row&7)
    #pragma unroll
    for (int it = 0; it < 16; ++it) {
        int m   = it * 256 + tid;       // 16B-bf16 chunk id, coalesced across tid
        int row = m >> 4;
        int cs  = m & 15;
        float4 a = Pc4[m * 2], bb = Pc4[m * 2 + 1];
        *(bf16x8*)(Plds + row * 256 + ((cs ^ (row & 7)) << 4)) = cvt8(a, bb);
    }
    {
        madd[tid] = mget(pmask, c * T_SZ + tid, isb) ? 0.0f : -1e30f;
        qmul[tid] = mget(qmask, b * T_SZ + tid, isb) ? 1.0f : 0.0f;
    }

    // Q fragments from fp32 (B operand: lane holds Q[q0+qt*16+lr][k*32+lg*8..+7])
    const int q0 = w * 64;
    bf16x8 qf[4][4];
    #pragma unroll
    for (int qt = 0; qt < 4; ++qt)
        #pragma unroll
        for (int k = 0; k < 4; ++k) {
            const float4* s = (const float4*)(Qb32 + (q0 + qt * 16 + lr) * D_SZ + k * 32 + lg * 8);
            qf[qt][k] = cvt8(s[0], s[1]);
        }

    __syncthreads();

    float rmax[4] = {-3e38f, -3e38f, -3e38f, -3e38f};

    for (int pt = 0; pt < 16; ++pt) {
        f32x4 acc[4];
        #pragma unroll
        for (int qt = 0; qt < 4; ++qt) acc[qt] = (f32x4){0.f, 0.f, 0.f, 0.f};
        #pragma unroll
        for (int k = 0; k < 4; ++k) {
            int row = pt * 16 + lr;
            bf16x8 af = *(const bf16x8*)(Plds + row * 256 + (((k * 4 + lg) ^ (row & 7)) << 4));
            #pragma unroll
            for (int qt = 0; qt < 4; ++qt)
                acc[qt] = __builtin_amdgcn_mfma_f32_16x16x32_bf16(af, qf[qt][k], acc[qt], 0, 0, 0);
        }
        // C layout: col(q)=lane&15, row(p)= pt*16 + (lane>>4)*4 + reg
        float pm0 = madd[pt * 16 + lg * 4 + 0];
        float pm1 = madd[pt * 16 + lg * 4 + 1];
        float pm2 = madd[pt * 16 + lg * 4 + 2];
        float pm3v = madd[pt * 16 + lg * 4 + 3];
        #pragma unroll
        for (int qt = 0; qt < 4; ++qt) {
            float m0 = fmaxf(fmaxf(acc[qt][0] + pm0, acc[qt][1] + pm1),
                             fmaxf(acc[qt][2] + pm2, acc[qt][3] + pm3v));
            rmax[qt] = fmaxf(rmax[qt], m0);
        }
    }

    // combine the 4 row-groups: lanes {x,16+x,32+x,48+x} hold partial maxes
    #pragma unroll
    for (int qt = 0; qt < 4; ++qt) {
        float v = rmax[qt];
        v = fmaxf(v, __shfl_xor(v, 16));
        v = fmaxf(v, __shfl_xor(v, 32));
        rmax[qt] = v;
    }
    // masked sum over this wave's 64 q tokens (each value replicated 4x)
    float tot = 0.f;
    #pragma unroll
    for (int qt = 0; qt < 4; ++qt) tot += rmax[qt] * qmul[q0 + qt * 16 + lr];
    #pragma unroll
    for (int off = 32; off > 0; off >>= 1) tot += __shfl_down(tot, off);
    if (l == 0) wsum[w] = tot * 0.25f;
    __syncthreads();

    if (tid == 0) {
        sraw[bid] = wsum[0] + wsum[1] + wsum[2] + wsum[3];
        __threadfence();                       // release sraw store
        unsigned int old = atomicAdd(counter, 1u);
        lastflag = (old == (unsigned int)(gridDim.x - 1));
    }
    __syncthreads();
    if (!lastflag) return;

    // ================== last block: dense sim + losses ==================
    __threadfence();                           // acquire all sraw stores

    // carve loss scratch out of the (now dead) P-tile LDS
    float* qsL   = (float*)Plds;               // [32][132] padded
    float* psL   = qsL + 32 * 132;             // [32][132]
    float* dense = psL + 32 * 132;             // [32][32]
    float* late  = dense + 32 * 32;            // [32][32]
    float* tcnt  = late + 32 * 32;             // [32]
    float* rsA   = tcnt + 32;
    float* rmA   = rsA + 32;
    float* rkA   = rmA + 32;

    // stage single vectors (pad 132 breaks the stride-128 bank pileup)
    for (int i = tid; i < 1024; i += 256) {
        int r = i >> 5, c4 = (i & 31) * 4;
        *(float4*)(qsL + r * 132 + c4) = *(const float4*)(qs + r * D_SZ + c4);
        *(float4*)(psL + r * 132 + c4) = *(const float4*)(ps + r * D_SZ + c4);
    }

    // token counts: 8 threads per row, shuffle-reduce
    {
        const int r = tid >> 3, j = tid & 7;
        int cnt = 0;
        if (isb) {
            const unsigned int* mm = (const unsigned int*)((const unsigned char*)qmask + r * T_SZ + j * 32);
            #pragma unroll
            for (int t = 0; t < 8; ++t) cnt += (int)((mm[t] * 0x01010101u) >> 24);
        } else {
            const int* mm = (const int*)qmask + r * T_SZ + j * 32;
            #pragma unroll
            for (int t = 0; t < 32; ++t) cnt += (mm[t] != 0);
        }
        cnt += __shfl_xor(cnt, 1);
        cnt += __shfl_xor(cnt, 2);
        cnt += __shfl_xor(cnt, 4);
        if (j == 0) tcnt[r] = (float)(cnt > 1 ? cnt : 1);
    }
    __syncthreads();

    // dense sim + scaled late sim: 4 (r,c) pairs per thread
    for (int idx = tid; idx < B_SZ * B_SZ; idx += 256) {
        int r = idx >> 5, cc = idx & 31;
        float s = 0.f;
        #pragma unroll
        for (int i = 0; i < D_SZ; i += 4) {
            float4 a  = *(const float4*)(qsL + r  * 132 + i);
            float4 bb = *(const float4*)(psL + cc * 132 + i);
            s += a.x * bb.x + a.y * bb.y + a.z * bb.z + a.w * bb.w;
        }
        dense[r * 32 + cc] = s;
        late[r * 32 + cc]  = sraw[idx] / tcnt[r];
    }
    __syncthreads();

    // per-row softmax/CE/KL: 8 rows at a time, 32 lanes per row
    const int cc = tid & 31;
    #pragma unroll
    for (int it = 0; it < 4; ++it) {
        const int r = (tid >> 5) + 8 * it;
        float xd = dense[r * 32 + cc] * TAU_INV;
        float xl = late[r * 32 + cc]  * TAU_INV;
        float md = xd, ml = xl;
        #pragma unroll
        for (int off = 16; off > 0; off >>= 1) {
            md = fmaxf(md, __shfl_xor(md, off));
            ml = fmaxf(ml, __shfl_xor(ml, off));
        }
        float sd = expf(xd - md), sl = expf(xl - ml);
        #pragma unroll
        for (int off = 16; off > 0; off >>= 1) {
            sd += __shfl_xor(sd, off);
            sl += __shfl_xor(sl, off);
        }
        float lsd = md + logf(sd);
        float lsl = ml + logf(sl);
        float pd = expf(xd - lsd);
        float pl = expf(xl - lsl);
        float klt = pd * logf((pd + 1e-8f) / (pl + 1e-8f));
        #pragma unroll
        for (int off = 16; off > 0; off >>= 1) klt += __shfl_xor(klt, off);
        if (cc == 0)  rkA[r] = klt;
        if (cc == r)  { rsA[r] = -(xd - lsd); rmA[r] = -(xl - lsl); }
    }
    __syncthreads();

    if (tid < B_SZ) {
        float a = rsA[tid], bb = rmA[tid], c2 = rkA[tid];
        #pragma unroll
        for (int off = 16; off > 0; off >>= 1) {
            a  += __shfl_xor(a, off);
            bb += __shfl_xor(bb, off);
            c2 += __shfl_xor(c2, off);
        }
        if (tid == 0) {
            a *= (1.0f / B_SZ); bb *= (1.0f / B_SZ); c2 *= (1.0f / B_SZ);
            out[0] = a + bb + c2;  // total
            out[1] = a;            // single_loss
            out[2] = bb;           // multi_loss
            out[3] = c2;           // kl
        }
    }
}

// ---------------------------------------------------------------------------
extern "C" void kernel_launch(void* const* d_in, const int* in_sizes, int n_in,
                              void* d_out, int out_size, void* d_ws, size_t ws_size,
                              hipStream_t stream) {
    const float* qs    = (const float*)d_in[0];  // query_single [32,128]
    const float* ps    = (const float*)d_in[1];  // pos_single   [32,128]
    const float* qm3   = (const float*)d_in[2];  // query_multi  [32,256,128]
    const float* pm3   = (const float*)d_in[3];  // pos_multi    [32,256,128]
    const void*  qmask = d_in[4];                // q_mask [32,256]
    const void*  pmask = d_in[5];                // p_mask [32,256]
    float* out = (float*)d_out;

    float* sraw = (float*)d_ws;                               // [1024]
    unsigned int* counter = (unsigned int*)((char*)d_ws + 4096);

    hipMemsetAsync(counter, 0, sizeof(unsigned int), stream); // graph-capturable node
    fused_all<<<B_SZ * B_SZ, 256, 0, stream>>>(qs, ps, qm3, pm3, qmask, pmask,
                                               sraw, counter, out);
}

// Round 4
// 44.646 us; speedup vs baseline: 1.6248x; 1.6248x over previous
//
#include <hip/hip_runtime.h>
#include <hip/hip_bf16.h>

// Problem constants (from reference): B=32, T=256, D=128, tau=0.02
#define B_SZ 32
#define T_SZ 256
#define D_SZ 128
#define TAU_INV 50.0f

typedef __bf16 bf16x8 __attribute__((ext_vector_type(8)));
typedef float f32x4 __attribute__((ext_vector_type(4)));

__device__ __forceinline__ unsigned short f2bf(float f) {
    union { float f; unsigned int u; } v; v.f = f;
    unsigned int r = v.u + 0x7fffu + ((v.u >> 16) & 1u);  // RNE
    return (unsigned short)(r >> 16);
}

// masks arrive either as int32 (harness "integer -> int*") or raw bool bytes.
// Element [0][0] is always true (q_len,p_len >= 64), so int32 layout reads 1,
// byte layout reads 0x01010101. Deterministic (input-only) detection.
__device__ __forceinline__ bool mask_is_byte(const void* m) {
    return ((const int*)m)[0] != 1;
}
__device__ __forceinline__ int mget(const void* m, int idx, bool isb) {
    return isb ? (((const unsigned char*)m)[idx] != 0) : (((const int*)m)[idx] != 0);
}

// ---------------- Kernel A: fp32 -> bf16, both arrays in one dispatch -------
__global__ __launch_bounds__(256) void cvt_both(
    const float* __restrict__ qsrc, const float* __restrict__ psrc,
    unsigned short* __restrict__ Qb, unsigned short* __restrict__ Pb) {
    const int half = blockIdx.x >> 10;                 // 0: Q, 1: P (uniform per block)
    const float* s = half ? psrc : qsrc;
    unsigned short* d = half ? Pb : Qb;
    int i = ((blockIdx.x & 1023) * 256 + threadIdx.x) * 4;
    float4 v = *(const float4*)(s + i);
    ushort4 o;
    o.x = f2bf(v.x); o.y = f2bf(v.y); o.z = f2bf(v.z); o.w = f2bf(v.w);
    *(ushort4*)(d + i) = o;
}

// ---------------- Kernel B: late-interaction + last-block losses ------------
// Block (c, bg): stages P_c once (64 KB bf16 LDS, XOR-swizzled), computes two
// b's (bg, bg+16). 8 waves x 32 q-rows each. Last block computes losses.
__global__ __launch_bounds__(512, 4) void late_fused(
    const float* __restrict__ qs,  const float* __restrict__ ps,
    const unsigned short* __restrict__ Qbf, const unsigned short* __restrict__ Pbf,
    const void* __restrict__ qmask, const void* __restrict__ pmask,
    float* __restrict__ sraw, unsigned int* __restrict__ counter,
    float* __restrict__ out)
{
    __shared__ __align__(16) unsigned char Plds[T_SZ * D_SZ * 2]; // 64 KB
    __shared__ float madd[T_SZ];     // 0 / -1e30 per p token (this c)
    __shared__ float qmul[2][T_SZ];  // 1 / 0 per q token (b0, b1)
    __shared__ float wsum[2][8];
    __shared__ int lastflag;

    const int tid = threadIdx.x;
    const int l   = tid & 63;
    const int w   = tid >> 6;        // wave 0..7
    const int bid = blockIdx.x;
    const int c   = bid & 31;
    const int bg  = bid >> 5;        // 0..15
    const int b0  = bg, b1 = bg + 16;
    const int lr  = l & 15;
    const int lg  = l >> 4;

    const bool isb = mask_is_byte(qmask);
    const unsigned short* Pc = Pbf + c * (T_SZ * D_SZ);

    // stage P tile: linear bf16 reads, chunk-swizzled LDS writes (cs ^= row&7)
    #pragma unroll
    for (int it = 0; it < 8; ++it) {
        int m   = it * 512 + tid;        // 16B chunk id, coalesced
        int row = m >> 4;
        int cs  = m & 15;
        bf16x8 v = *(const bf16x8*)(Pc + m * 8);
        *(bf16x8*)(Plds + row * 256 + ((cs ^ (row & 7)) << 4)) = v;
    }
    {
        int t = tid & 255;
        if (tid < 256) madd[t] = mget(pmask, c * T_SZ + t, isb) ? 0.0f : -1e30f;
        qmul[tid >> 8][t] = mget(qmask, (tid < 256 ? b0 : b1) * T_SZ + t, isb) ? 1.0f : 0.0f;
    }

    // Q fragments for both b's: lane holds Q[w*32+qt*16+lr][k*32+lg*8 .. +7]
    bf16x8 qf0[2][4], qf1[2][4];
    #pragma unroll
    for (int qt = 0; qt < 2; ++qt)
        #pragma unroll
        for (int k = 0; k < 4; ++k) {
            int roff = (w * 32 + qt * 16 + lr) * D_SZ + k * 32 + lg * 8;
            qf0[qt][k] = *(const bf16x8*)(Qbf + b0 * (T_SZ * D_SZ) + roff);
            qf1[qt][k] = *(const bf16x8*)(Qbf + b1 * (T_SZ * D_SZ) + roff);
        }

    __syncthreads();

    float r00 = -3e38f, r01 = -3e38f, r10 = -3e38f, r11 = -3e38f;

    for (int pt = 0; pt < 16; ++pt) {
        f32x4 a00 = {0,0,0,0}, a01 = {0,0,0,0}, a10 = {0,0,0,0}, a11 = {0,0,0,0};
        #pragma unroll
        for (int k = 0; k < 4; ++k) {
            int row = pt * 16 + lr;
            bf16x8 af = *(const bf16x8*)(Plds + row * 256 + (((k * 4 + lg) ^ (row & 7)) << 4));
            a00 = __builtin_amdgcn_mfma_f32_16x16x32_bf16(af, qf0[0][k], a00, 0, 0, 0);
            a01 = __builtin_amdgcn_mfma_f32_16x16x32_bf16(af, qf0[1][k], a01, 0, 0, 0);
            a10 = __builtin_amdgcn_mfma_f32_16x16x32_bf16(af, qf1[0][k], a10, 0, 0, 0);
            a11 = __builtin_amdgcn_mfma_f32_16x16x32_bf16(af, qf1[1][k], a11, 0, 0, 0);
        }
        // C layout: col(q)=lane&15, row(p)= pt*16 + lg*4 + reg
        float pm0 = madd[pt * 16 + lg * 4 + 0];
        float pm1 = madd[pt * 16 + lg * 4 + 1];
        float pm2 = madd[pt * 16 + lg * 4 + 2];
        float pm3 = madd[pt * 16 + lg * 4 + 3];
        r00 = fmaxf(r00, fmaxf(fmaxf(a00[0]+pm0, a00[1]+pm1), fmaxf(a00[2]+pm2, a00[3]+pm3)));
        r01 = fmaxf(r01, fmaxf(fmaxf(a01[0]+pm0, a01[1]+pm1), fmaxf(a01[2]+pm2, a01[3]+pm3)));
        r10 = fmaxf(r10, fmaxf(fmaxf(a10[0]+pm0, a10[1]+pm1), fmaxf(a10[2]+pm2, a10[3]+pm3)));
        r11 = fmaxf(r11, fmaxf(fmaxf(a11[0]+pm0, a11[1]+pm1), fmaxf(a11[2]+pm2, a11[3]+pm3)));
    }

    // combine the 4 row-groups (lanes x, 16+x, 32+x, 48+x)
    r00 = fmaxf(r00, __shfl_xor(r00, 16)); r00 = fmaxf(r00, __shfl_xor(r00, 32));
    r01 = fmaxf(r01, __shfl_xor(r01, 16)); r01 = fmaxf(r01, __shfl_xor(r01, 32));
    r10 = fmaxf(r10, __shfl_xor(r10, 16)); r10 = fmaxf(r10, __shfl_xor(r10, 32));
    r11 = fmaxf(r11, __shfl_xor(r11, 16)); r11 = fmaxf(r11, __shfl_xor(r11, 32));

    // masked sum over this wave's 32 q tokens (each value replicated 4x)
    float t0 = r00 * qmul[0][w * 32 + lr] + r01 * qmul[0][w * 32 + 16 + lr];
    float t1 = r10 * qmul[1][w * 32 + lr] + r11 * qmul[1][w * 32 + 16 + lr];
    #pragma unroll
    for (int off = 32; off > 0; off >>= 1) {
        t0 += __shfl_down(t0, off);
        t1 += __shfl_down(t1, off);
    }
    if (l == 0) { wsum[0][w] = t0 * 0.25f; wsum[1][w] = t1 * 0.25f; }
    __syncthreads();

    if (tid == 0) {
        float s0 = 0.f, s1 = 0.f;
        #pragma unroll
        for (int ww = 0; ww < 8; ++ww) { s0 += wsum[0][ww]; s1 += wsum[1][ww]; }
        sraw[b0 * 32 + c] = s0;
        sraw[b1 * 32 + c] = s1;
        __threadfence();                        // release sraw stores
        unsigned int old = atomicAdd(counter, 1u);
        lastflag = (old == (unsigned int)(gridDim.x - 1));
    }
    __syncthreads();
    if (!lastflag) return;

    // ================== last block: dense sim + losses ==================
    __threadfence();                            // acquire all sraw stores

    float* qsL   = (float*)Plds;                // [32][132] padded
    float* psL   = qsL + 32 * 132;              // [32][132]
    float* dense = psL + 32 * 132;              // [32][32]
    float* late  = dense + 32 * 32;             // [32][32]
    float* tcnt  = late + 32 * 32;              // [32]
    float* rsA   = tcnt + 32;
    float* rmA   = rsA + 32;
    float* rkA   = rmA + 32;

    for (int i = tid; i < 1024; i += 512) {     // 1024 float4 slots per array
        int r = i >> 5, c4 = (i & 31) * 4;
        *(float4*)(qsL + r * 132 + c4) = *(const float4*)(qs + r * D_SZ + c4);
        *(float4*)(psL + r * 132 + c4) = *(const float4*)(ps + r * D_SZ + c4);
    }
    if (tid < 256) {                            // token counts, 8 threads/row
        const int r = tid >> 3, j = tid & 7;
        int cnt = 0;
        if (isb) {
            const unsigned int* mm = (const unsigned int*)((const unsigned char*)qmask + r * T_SZ + j * 32);
            #pragma unroll
            for (int t = 0; t < 8; ++t) cnt += (int)((mm[t] * 0x01010101u) >> 24);
        } else {
            const int* mm = (const int*)qmask + r * T_SZ + j * 32;
            #pragma unroll
            for (int t = 0; t < 32; ++t) cnt += (mm[t] != 0);
        }
        cnt += __shfl_xor(cnt, 1);
        cnt += __shfl_xor(cnt, 2);
        cnt += __shfl_xor(cnt, 4);
        if (j == 0) tcnt[r] = (float)(cnt > 1 ? cnt : 1);
    }
    __syncthreads();

    for (int idx = tid; idx < B_SZ * B_SZ; idx += 512) {  // 2 (r,c) pairs/thread
        int r = idx >> 5, cc = idx & 31;
        float s = 0.f;
        #pragma unroll
        for (int i = 0; i < D_SZ; i += 4) {
            float4 a  = *(const float4*)(qsL + r  * 132 + i);
            float4 bb = *(const float4*)(psL + cc * 132 + i);
            s += a.x * bb.x + a.y * bb.y + a.z * bb.z + a.w * bb.w;
        }
        dense[r * 32 + cc] = s;
        late[r * 32 + cc]  = sraw[idx] / tcnt[r];
    }
    __syncthreads();

    // per-row softmax/CE/KL: 16 rows per pass, 32 lanes per row
    {
        const int cc = tid & 31;
        #pragma unroll
        for (int it = 0; it < 2; ++it) {
            const int r = (tid >> 5) + 16 * it;
            float xd = dense[r * 32 + cc] * TAU_INV;
            float xl = late[r * 32 + cc]  * TAU_INV;
            float md = xd, ml = xl;
            #pragma unroll
            for (int off = 16; off > 0; off >>= 1) {
                md = fmaxf(md, __shfl_xor(md, off));
                ml = fmaxf(ml, __shfl_xor(ml, off));
            }
            float sd = expf(xd - md), sl = expf(xl - ml);
            #pragma unroll
            for (int off = 16; off > 0; off >>= 1) {
                sd += __shfl_xor(sd, off);
                sl += __shfl_xor(sl, off);
            }
            float lsd = md + logf(sd);
            float lsl = ml + logf(sl);
            float pd = expf(xd - lsd);
            float pl = expf(xl - lsl);
            float klt = pd * logf((pd + 1e-8f) / (pl + 1e-8f));
            #pragma unroll
            for (int off = 16; off > 0; off >>= 1) klt += __shfl_xor(klt, off);
            if (cc == 0) rkA[r] = klt;
            if (cc == r) { rsA[r] = -(xd - lsd); rmA[r] = -(xl - lsl); }
        }
    }
    __syncthreads();

    if (tid < B_SZ) {
        float a = rsA[tid], bb = rmA[tid], c2 = rkA[tid];
        #pragma unroll
        for (int off = 16; off > 0; off >>= 1) {
            a  += __shfl_xor(a, off);
            bb += __shfl_xor(bb, off);
            c2 += __shfl_xor(c2, off);
        }
        if (tid == 0) {
            a *= (1.0f / B_SZ); bb *= (1.0f / B_SZ); c2 *= (1.0f / B_SZ);
            out[0] = a + bb + c2;  // total
            out[1] = a;            // single_loss
            out[2] = bb;           // multi_loss
            out[3] = c2;           // kl
        }
    }
}

// ---------------------------------------------------------------------------
extern "C" void kernel_launch(void* const* d_in, const int* in_sizes, int n_in,
                              void* d_out, int out_size, void* d_ws, size_t ws_size,
                              hipStream_t stream) {
    const float* qs    = (const float*)d_in[0];  // query_single [32,128]
    const float* ps    = (const float*)d_in[1];  // pos_single   [32,128]
    const float* qm3   = (const float*)d_in[2];  // query_multi  [32,256,128]
    const float* pm3   = (const float*)d_in[3];  // pos_multi    [32,256,128]
    const void*  qmask = d_in[4];                // q_mask [32,256]
    const void*  pmask = d_in[5];                // p_mask [32,256]
    float* out = (float*)d_out;

    const int NTOK = B_SZ * T_SZ * D_SZ;         // 1,048,576
    unsigned short* Qbf = (unsigned short*)d_ws;
    unsigned short* Pbf = Qbf + NTOK;
    float* sraw = (float*)(Pbf + NTOK);                       // [1024]
    unsigned int* counter = (unsigned int*)(sraw + 1024);

    hipMemsetAsync(counter, 0, sizeof(unsigned int), stream); // graph-capturable node
    cvt_both<<<2048, 256, 0, stream>>>(qm3, pm3, Qbf, Pbf);
    late_fused<<<512, 512, 0, stream>>>(qs, ps, Qbf, Pbf, qmask, pmask,
                                        sraw, counter, out);
}

// Round 5
// 39.517 us; speedup vs baseline: 1.8357x; 1.1298x over previous
//
#include <hip/hip_runtime.h>
#include <hip/hip_bf16.h>

// Problem constants (from reference): B=32, T=256, D=128, tau=0.02
#define B_SZ 32
#define T_SZ 256
#define D_SZ 128
#define TAU_INV 50.0f

typedef __bf16 bf16x8 __attribute__((ext_vector_type(8)));
typedef float f32x4 __attribute__((ext_vector_type(4)));

__device__ __forceinline__ unsigned short f2bf(float f) {
    union { float f; unsigned int u; } v; v.f = f;
    unsigned int r = v.u + 0x7fffu + ((v.u >> 16) & 1u);  // RNE
    return (unsigned short)(r >> 16);
}

// masks arrive either as int32 (harness "integer -> int*") or raw bool bytes.
// Element [0][0] is always true (q_len,p_len >= 64), so int32 layout reads 1,
// byte layout reads 0x01010101. Deterministic (input-only) detection.
__device__ __forceinline__ bool mask_is_byte(const void* m) {
    return ((const int*)m)[0] != 1;
}
__device__ __forceinline__ int mget(const void* m, int idx, bool isb) {
    return isb ? (((const unsigned char*)m)[idx] != 0) : (((const int*)m)[idx] != 0);
}

// ---------------- Kernel A: fp32 -> bf16, both arrays in one dispatch -------
__global__ __launch_bounds__(256) void cvt_both(
    const float* __restrict__ qsrc, const float* __restrict__ psrc,
    unsigned short* __restrict__ Qb, unsigned short* __restrict__ Pb) {
    const int half = blockIdx.x >> 10;                 // 0: Q, 1: P (uniform per block)
    const float* s = half ? psrc : qsrc;
    unsigned short* d = half ? Pb : Qb;
    int i = ((blockIdx.x & 1023) * 256 + threadIdx.x) * 4;
    float4 v = *(const float4*)(s + i);
    ushort4 o;
    o.x = f2bf(v.x); o.y = f2bf(v.y); o.z = f2bf(v.z); o.w = f2bf(v.w);
    *(ushort4*)(d + i) = o;
}

// ---------------- Kernel B: late-interaction scores (no atomics) ------------
// Block (c, bg): stages P_c once (64 KB bf16 LDS, XOR-swizzled), computes two
// b's (bg, bg+16). 8 waves x 32 q-rows each.
__global__ __launch_bounds__(512, 4) void late_sim(
    const unsigned short* __restrict__ Qbf, const unsigned short* __restrict__ Pbf,
    const void* __restrict__ qmask, const void* __restrict__ pmask,
    float* __restrict__ sraw)
{
    __shared__ __align__(16) unsigned char Plds[T_SZ * D_SZ * 2]; // 64 KB
    __shared__ float madd[T_SZ];     // 0 / -1e30 per p token (this c)
    __shared__ float qmul[2][T_SZ];  // 1 / 0 per q token (b0, b1)
    __shared__ float wsum[2][8];

    const int tid = threadIdx.x;
    const int l   = tid & 63;
    const int w   = tid >> 6;        // wave 0..7
    const int bid = blockIdx.x;
    const int c   = bid & 31;
    const int bg  = bid >> 5;        // 0..15
    const int b0  = bg, b1 = bg + 16;
    const int lr  = l & 15;
    const int lg  = l >> 4;

    const bool isb = mask_is_byte(qmask);
    const unsigned short* Pc = Pbf + c * (T_SZ * D_SZ);

    // stage P tile: linear bf16 reads, chunk-swizzled LDS writes (cs ^= row&7)
    #pragma unroll
    for (int it = 0; it < 8; ++it) {
        int m   = it * 512 + tid;        // 16B chunk id, coalesced
        int row = m >> 4;
        int cs  = m & 15;
        bf16x8 v = *(const bf16x8*)(Pc + m * 8);
        *(bf16x8*)(Plds + row * 256 + ((cs ^ (row & 7)) << 4)) = v;
    }
    {
        int t = tid & 255;
        if (tid < 256) madd[t] = mget(pmask, c * T_SZ + t, isb) ? 0.0f : -1e30f;
        qmul[tid >> 8][t] = mget(qmask, (tid < 256 ? b0 : b1) * T_SZ + t, isb) ? 1.0f : 0.0f;
    }

    // Q fragments for both b's: lane holds Q[w*32+qt*16+lr][k*32+lg*8 .. +7]
    bf16x8 qf0[2][4], qf1[2][4];
    #pragma unroll
    for (int qt = 0; qt < 2; ++qt)
        #pragma unroll
        for (int k = 0; k < 4; ++k) {
            int roff = (w * 32 + qt * 16 + lr) * D_SZ + k * 32 + lg * 8;
            qf0[qt][k] = *(const bf16x8*)(Qbf + b0 * (T_SZ * D_SZ) + roff);
            qf1[qt][k] = *(const bf16x8*)(Qbf + b1 * (T_SZ * D_SZ) + roff);
        }

    __syncthreads();

    float r00 = -3e38f, r01 = -3e38f, r10 = -3e38f, r11 = -3e38f;

    for (int pt = 0; pt < 16; ++pt) {
        f32x4 a00 = {0,0,0,0}, a01 = {0,0,0,0}, a10 = {0,0,0,0}, a11 = {0,0,0,0};
        #pragma unroll
        for (int k = 0; k < 4; ++k) {
            int row = pt * 16 + lr;
            bf16x8 af = *(const bf16x8*)(Plds + row * 256 + (((k * 4 + lg) ^ (row & 7)) << 4));
            a00 = __builtin_amdgcn_mfma_f32_16x16x32_bf16(af, qf0[0][k], a00, 0, 0, 0);
            a01 = __builtin_amdgcn_mfma_f32_16x16x32_bf16(af, qf0[1][k], a01, 0, 0, 0);
            a10 = __builtin_amdgcn_mfma_f32_16x16x32_bf16(af, qf1[0][k], a10, 0, 0, 0);
            a11 = __builtin_amdgcn_mfma_f32_16x16x32_bf16(af, qf1[1][k], a11, 0, 0, 0);
        }
        // C layout: col(q)=lane&15, row(p)= pt*16 + lg*4 + reg
        float pm0 = madd[pt * 16 + lg * 4 + 0];
        float pm1 = madd[pt * 16 + lg * 4 + 1];
        float pm2 = madd[pt * 16 + lg * 4 + 2];
        float pm3 = madd[pt * 16 + lg * 4 + 3];
        r00 = fmaxf(r00, fmaxf(fmaxf(a00[0]+pm0, a00[1]+pm1), fmaxf(a00[2]+pm2, a00[3]+pm3)));
        r01 = fmaxf(r01, fmaxf(fmaxf(a01[0]+pm0, a01[1]+pm1), fmaxf(a01[2]+pm2, a01[3]+pm3)));
        r10 = fmaxf(r10, fmaxf(fmaxf(a10[0]+pm0, a10[1]+pm1), fmaxf(a10[2]+pm2, a10[3]+pm3)));
        r11 = fmaxf(r11, fmaxf(fmaxf(a11[0]+pm0, a11[1]+pm1), fmaxf(a11[2]+pm2, a11[3]+pm3)));
    }

    // combine the 4 row-groups (lanes x, 16+x, 32+x, 48+x)
    r00 = fmaxf(r00, __shfl_xor(r00, 16)); r00 = fmaxf(r00, __shfl_xor(r00, 32));
    r01 = fmaxf(r01, __shfl_xor(r01, 16)); r01 = fmaxf(r01, __shfl_xor(r01, 32));
    r10 = fmaxf(r10, __shfl_xor(r10, 16)); r10 = fmaxf(r10, __shfl_xor(r10, 32));
    r11 = fmaxf(r11, __shfl_xor(r11, 16)); r11 = fmaxf(r11, __shfl_xor(r11, 32));

    // masked sum over this wave's 32 q tokens (each value replicated 4x)
    float t0 = r00 * qmul[0][w * 32 + lr] + r01 * qmul[0][w * 32 + 16 + lr];
    float t1 = r10 * qmul[1][w * 32 + lr] + r11 * qmul[1][w * 32 + 16 + lr];
    #pragma unroll
    for (int off = 32; off > 0; off >>= 1) {
        t0 += __shfl_down(t0, off);
        t1 += __shfl_down(t1, off);
    }
    if (l == 0) { wsum[0][w] = t0 * 0.25f; wsum[1][w] = t1 * 0.25f; }
    __syncthreads();

    if (tid == 0) {
        float s0 = 0.f, s1 = 0.f;
        #pragma unroll
        for (int ww = 0; ww < 8; ++ww) { s0 += wsum[0][ww]; s1 += wsum[1][ww]; }
        sraw[b0 * 32 + c] = s0;
        sraw[b1 * 32 + c] = s1;
    }
}

// ---------------- Kernel C: dense sim + losses (1 block, parallel) ----------
__global__ __launch_bounds__(256) void loss_final(
    const float* __restrict__ qs, const float* __restrict__ ps,
    const float* __restrict__ sraw, const void* __restrict__ qmask,
    float* __restrict__ out)
{
    __shared__ float qsL[B_SZ * 132];
    __shared__ float psL[B_SZ * 132];
    __shared__ float dense[B_SZ * B_SZ];
    __shared__ float late[B_SZ * B_SZ];
    __shared__ float tcnt[B_SZ];
    __shared__ float rsA[B_SZ], rmA[B_SZ], rkA[B_SZ];

    const int tid = threadIdx.x;
    const bool isb = mask_is_byte(qmask);

    for (int i = tid; i < 1024; i += 256) {     // 1024 float4 slots per array
        int r = i >> 5, c4 = (i & 31) * 4;
        *(float4*)(qsL + r * 132 + c4) = *(const float4*)(qs + r * D_SZ + c4);
        *(float4*)(psL + r * 132 + c4) = *(const float4*)(ps + r * D_SZ + c4);
    }
    {                                           // token counts, 8 threads/row
        const int r = tid >> 3, j = tid & 7;
        int cnt = 0;
        if (isb) {
            const unsigned int* mm = (const unsigned int*)((const unsigned char*)qmask + r * T_SZ + j * 32);
            #pragma unroll
            for (int t = 0; t < 8; ++t) cnt += (int)((mm[t] * 0x01010101u) >> 24);
        } else {
            const int* mm = (const int*)qmask + r * T_SZ + j * 32;
            #pragma unroll
            for (int t = 0; t < 32; ++t) cnt += (mm[t] != 0);
        }
        cnt += __shfl_xor(cnt, 1);
        cnt += __shfl_xor(cnt, 2);
        cnt += __shfl_xor(cnt, 4);
        if (j == 0) tcnt[r] = (float)(cnt > 1 ? cnt : 1);
    }
    __syncthreads();

    for (int idx = tid; idx < B_SZ * B_SZ; idx += 256) {  // 4 (r,c) pairs/thread
        int r = idx >> 5, cc = idx & 31;
        float s = 0.f;
        #pragma unroll
        for (int i = 0; i < D_SZ; i += 4) {
            float4 a  = *(const float4*)(qsL + r  * 132 + i);
            float4 bb = *(const float4*)(psL + cc * 132 + i);
            s += a.x * bb.x + a.y * bb.y + a.z * bb.z + a.w * bb.w;
        }
        dense[r * 32 + cc] = s;
        late[r * 32 + cc]  = sraw[idx] / tcnt[r];
    }
    __syncthreads();

    // per-row softmax/CE/KL: 8 rows per pass, 32 lanes per row
    {
        const int cc = tid & 31;
        #pragma unroll
        for (int it = 0; it < 4; ++it) {
            const int r = (tid >> 5) + 8 * it;
            float xd = dense[r * 32 + cc] * TAU_INV;
            float xl = late[r * 32 + cc]  * TAU_INV;
            float md = xd, ml = xl;
            #pragma unroll
            for (int off = 16; off > 0; off >>= 1) {
                md = fmaxf(md, __shfl_xor(md, off));
                ml = fmaxf(ml, __shfl_xor(ml, off));
            }
            float sd = expf(xd - md), sl = expf(xl - ml);
            #pragma unroll
            for (int off = 16; off > 0; off >>= 1) {
                sd += __shfl_xor(sd, off);
                sl += __shfl_xor(sl, off);
            }
            float lsd = md + logf(sd);
            float lsl = ml + logf(sl);
            float pd = expf(xd - lsd);
            float pl = expf(xl - lsl);
            float klt = pd * logf((pd + 1e-8f) / (pl + 1e-8f));
            #pragma unroll
            for (int off = 16; off > 0; off >>= 1) klt += __shfl_xor(klt, off);
            if (cc == 0) rkA[r] = klt;
            if (cc == r) { rsA[r] = -(xd - lsd); rmA[r] = -(xl - lsl); }
        }
    }
    __syncthreads();

    if (tid < B_SZ) {
        float a = rsA[tid], bb = rmA[tid], c2 = rkA[tid];
        #pragma unroll
        for (int off = 16; off > 0; off >>= 1) {
            a  += __shfl_xor(a, off);
            bb += __shfl_xor(bb, off);
            c2 += __shfl_xor(c2, off);
        }
        if (tid == 0) {
            a *= (1.0f / B_SZ); bb *= (1.0f / B_SZ); c2 *= (1.0f / B_SZ);
            out[0] = a + bb + c2;  // total
            out[1] = a;            // single_loss
            out[2] = bb;           // multi_loss
            out[3] = c2;           // kl
        }
    }
}

// ---------------------------------------------------------------------------
extern "C" void kernel_launch(void* const* d_in, const int* in_sizes, int n_in,
                              void* d_out, int out_size, void* d_ws, size_t ws_size,
                              hipStream_t stream) {
    const float* qs    = (const float*)d_in[0];  // query_single [32,128]
    const float* ps    = (const float*)d_in[1];  // pos_single   [32,128]
    const float* qm3   = (const float*)d_in[2];  // query_multi  [32,256,128]
    const float* pm3   = (const float*)d_in[3];  // pos_multi    [32,256,128]
    const void*  qmask = d_in[4];                // q_mask [32,256]
    const void*  pmask = d_in[5];                // p_mask [32,256]
    float* out = (float*)d_out;

    const int NTOK = B_SZ * T_SZ * D_SZ;         // 1,048,576
    unsigned short* Qbf = (unsigned short*)d_ws;
    unsigned short* Pbf = Qbf + NTOK;
    float* sraw = (float*)(Pbf + NTOK);          // [1024]

    cvt_both<<<2048, 256, 0, stream>>>(qm3, pm3, Qbf, Pbf);
    late_sim<<<512, 512, 0, stream>>>(Qbf, Pbf, qmask, pmask, sraw);
    loss_final<<<1, 256, 0, stream>>>(qs, ps, sraw, qmask, out);
}

// Round 6
// 39.395 us; speedup vs baseline: 1.8413x; 1.0031x over previous
//
#include <hip/hip_runtime.h>
#include <hip/hip_bf16.h>

// Problem constants (from reference): B=32, T=256, D=128, tau=0.02
#define B_SZ 32
#define T_SZ 256
#define D_SZ 128
#define TAU_INV 50.0f

typedef __bf16 bf16x8 __attribute__((ext_vector_type(8)));
typedef float f32x4 __attribute__((ext_vector_type(4)));

__device__ __forceinline__ unsigned short f2bf(float f) {
    union { float f; unsigned int u; } v; v.f = f;
    unsigned int r = v.u + 0x7fffu + ((v.u >> 16) & 1u);  // RNE
    return (unsigned short)(r >> 16);
}

// masks arrive either as int32 (harness "integer -> int*") or raw bool bytes.
// Element [0][0] is always true (q_len,p_len >= 64), so int32 layout reads 1,
// byte layout reads 0x01010101. Deterministic (input-only) detection.
__device__ __forceinline__ bool mask_is_byte(const void* m) {
    return ((const int*)m)[0] != 1;
}
__device__ __forceinline__ int mget(const void* m, int idx, bool isb) {
    return isb ? (((const unsigned char*)m)[idx] != 0) : (((const int*)m)[idx] != 0);
}

// ---------------- Kernel A: fp32 -> bf16, both arrays in one dispatch -------
__global__ __launch_bounds__(256) void cvt_both(
    const float* __restrict__ qsrc, const float* __restrict__ psrc,
    unsigned short* __restrict__ Qb, unsigned short* __restrict__ Pb) {
    const int half = blockIdx.x >> 10;                 // 0: Q, 1: P (uniform per block)
    const float* s = half ? psrc : qsrc;
    unsigned short* d = half ? Pb : Qb;
    int i = ((blockIdx.x & 1023) * 256 + threadIdx.x) * 4;
    float4 v = *(const float4*)(s + i);
    ushort4 o;
    o.x = f2bf(v.x); o.y = f2bf(v.y); o.z = f2bf(v.z); o.w = f2bf(v.w);
    *(ushort4*)(d + i) = o;
}

// ---------------- Kernel B: late-interaction, pipelined P staging -----------
// Block (c, bg): streams P_c through a 2x16KB double-buffered LDS ring
// (64 p-rows per chunk), computes two b's (bg, bg+16). 8 waves x 32 q-rows.
// Per chunk: issue next chunk's global loads -> MFMA on current -> ds_write
// landed regs (vmcnt hidden under MFMA, T14) -> one barrier.
__global__ __launch_bounds__(512, 4) void late_sim(
    const unsigned short* __restrict__ Qbf, const unsigned short* __restrict__ Pbf,
    const void* __restrict__ qmask, const void* __restrict__ pmask,
    float* __restrict__ sraw)
{
    __shared__ __align__(16) unsigned char Plds[2][64 * 256]; // 2 x 16 KB
    __shared__ float madd[T_SZ];     // 0 / -1e30 per p token (this c)
    __shared__ float qmul[2][T_SZ];  // 1 / 0 per q token (b0, b1)
    __shared__ float wsum[2][8];

    const int tid = threadIdx.x;
    const int l   = tid & 63;
    const int w   = tid >> 6;        // wave 0..7
    const int bid = blockIdx.x;
    const int c   = bid & 31;
    const int bg  = bid >> 5;        // 0..15
    const int b0  = bg, b1 = bg + 16;
    const int lr  = l & 15;
    const int lg  = l >> 4;

    const bool isb = mask_is_byte(qmask);
    const unsigned short* Pc = Pbf + c * (T_SZ * D_SZ);

    // per-thread staging slots: 16 KB chunk = 512 thr x 32 B (two 16B units)
    const int m0 = tid, m1 = 512 + tid;                 // 16B unit ids in chunk
    const int r0 = m0 >> 4, cs0 = m0 & 15;              // local row 0..63
    const int r1 = m1 >> 4, cs1 = m1 & 15;
    const int w0 = r0 * 256 + ((cs0 ^ (r0 & 7)) << 4);  // swizzled LDS byte offs
    const int w1 = r1 * 256 + ((cs1 ^ (r1 & 7)) << 4);

    // ---- prologue: issue chunk-0 loads, then masks + Q frags, then write ----
    const bf16x8* src0 = (const bf16x8*)Pc;             // chunk 0 (rows 0..63)
    bf16x8 p0 = src0[m0], p1 = src0[m1];

    {
        int t = tid & 255;
        if (tid < 256) madd[t] = mget(pmask, c * T_SZ + t, isb) ? 0.0f : -1e30f;
        qmul[tid >> 8][t] = mget(qmask, (tid < 256 ? b0 : b1) * T_SZ + t, isb) ? 1.0f : 0.0f;
    }

    // Q fragments for both b's: lane holds Q[w*32+qt*16+lr][k*32+lg*8 .. +7]
    bf16x8 qf0[2][4], qf1[2][4];
    #pragma unroll
    for (int qt = 0; qt < 2; ++qt)
        #pragma unroll
        for (int k = 0; k < 4; ++k) {
            int roff = (w * 32 + qt * 16 + lr) * D_SZ + k * 32 + lg * 8;
            qf0[qt][k] = *(const bf16x8*)(Qbf + b0 * (T_SZ * D_SZ) + roff);
            qf1[qt][k] = *(const bf16x8*)(Qbf + b1 * (T_SZ * D_SZ) + roff);
        }

    *(bf16x8*)(Plds[0] + w0) = p0;
    *(bf16x8*)(Plds[0] + w1) = p1;
    __syncthreads();

    float r00 = -3e38f, r01 = -3e38f, r10 = -3e38f, r11 = -3e38f;

    // ---- main loop: 4 chunks of 64 p-rows, double-buffered ----
    #pragma unroll
    for (int ch = 0; ch < 4; ++ch) {
        bf16x8 s0, s1;
        if (ch < 3) {                                   // issue next-chunk loads
            const bf16x8* src = (const bf16x8*)(Pc + (ch + 1) * (64 * D_SZ));
            s0 = src[m0]; s1 = src[m1];
        }
        const unsigned char* buf = Plds[ch & 1];
        #pragma unroll
        for (int ptl = 0; ptl < 4; ++ptl) {
            f32x4 a00 = {0,0,0,0}, a01 = {0,0,0,0}, a10 = {0,0,0,0}, a11 = {0,0,0,0};
            #pragma unroll
            for (int k = 0; k < 4; ++k) {
                int lrow = ptl * 16 + lr;
                bf16x8 af = *(const bf16x8*)(buf + lrow * 256 + (((k * 4 + lg) ^ (lrow & 7)) << 4));
                a00 = __builtin_amdgcn_mfma_f32_16x16x32_bf16(af, qf0[0][k], a00, 0, 0, 0);
                a01 = __builtin_amdgcn_mfma_f32_16x16x32_bf16(af, qf0[1][k], a01, 0, 0, 0);
                a10 = __builtin_amdgcn_mfma_f32_16x16x32_bf16(af, qf1[0][k], a10, 0, 0, 0);
                a11 = __builtin_amdgcn_mfma_f32_16x16x32_bf16(af, qf1[1][k], a11, 0, 0, 0);
            }
            // C layout: col(q)=lane&15, row(p)= ch*64 + ptl*16 + lg*4 + reg
            int grow = ch * 64 + ptl * 16 + lg * 4;
            float pm0 = madd[grow + 0];
            float pm1 = madd[grow + 1];
            float pm2 = madd[grow + 2];
            float pm3 = madd[grow + 3];
            r00 = fmaxf(r00, fmaxf(fmaxf(a00[0]+pm0, a00[1]+pm1), fmaxf(a00[2]+pm2, a00[3]+pm3)));
            r01 = fmaxf(r01, fmaxf(fmaxf(a01[0]+pm0, a01[1]+pm1), fmaxf(a01[2]+pm2, a01[3]+pm3)));
            r10 = fmaxf(r10, fmaxf(fmaxf(a10[0]+pm0, a10[1]+pm1), fmaxf(a10[2]+pm2, a10[3]+pm3)));
            r11 = fmaxf(r11, fmaxf(fmaxf(a11[0]+pm0, a11[1]+pm1), fmaxf(a11[2]+pm2, a11[3]+pm3)));
        }
        if (ch < 3) {                                   // write landed regs (T14)
            unsigned char* nbuf = Plds[(ch + 1) & 1];
            *(bf16x8*)(nbuf + w0) = s0;
            *(bf16x8*)(nbuf + w1) = s1;
            __syncthreads();
        }
    }

    // combine the 4 row-groups (lanes x, 16+x, 32+x, 48+x)
    r00 = fmaxf(r00, __shfl_xor(r00, 16)); r00 = fmaxf(r00, __shfl_xor(r00, 32));
    r01 = fmaxf(r01, __shfl_xor(r01, 16)); r01 = fmaxf(r01, __shfl_xor(r01, 32));
    r10 = fmaxf(r10, __shfl_xor(r10, 16)); r10 = fmaxf(r10, __shfl_xor(r10, 32));
    r11 = fmaxf(r11, __shfl_xor(r11, 16)); r11 = fmaxf(r11, __shfl_xor(r11, 32));

    // masked sum over this wave's 32 q tokens (each value replicated 4x)
    float t0 = r00 * qmul[0][w * 32 + lr] + r01 * qmul[0][w * 32 + 16 + lr];
    float t1 = r10 * qmul[1][w * 32 + lr] + r11 * qmul[1][w * 32 + 16 + lr];
    #pragma unroll
    for (int off = 32; off > 0; off >>= 1) {
        t0 += __shfl_down(t0, off);
        t1 += __shfl_down(t1, off);
    }
    if (l == 0) { wsum[0][w] = t0 * 0.25f; wsum[1][w] = t1 * 0.25f; }
    __syncthreads();

    if (tid == 0) {
        float s0 = 0.f, s1 = 0.f;
        #pragma unroll
        for (int ww = 0; ww < 8; ++ww) { s0 += wsum[0][ww]; s1 += wsum[1][ww]; }
        sraw[b0 * 32 + c] = s0;
        sraw[b1 * 32 + c] = s1;
    }
}

// ---------------- Kernel C: dense sim + losses (1 block, parallel) ----------
__global__ __launch_bounds__(256) void loss_final(
    const float* __restrict__ qs, const float* __restrict__ ps,
    const float* __restrict__ sraw, const void* __restrict__ qmask,
    float* __restrict__ out)
{
    __shared__ float qsL[B_SZ * 132];
    __shared__ float psL[B_SZ * 132];
    __shared__ float dense[B_SZ * B_SZ];
    __shared__ float late[B_SZ * B_SZ];
    __shared__ float tcnt[B_SZ];
    __shared__ float rsA[B_SZ], rmA[B_SZ], rkA[B_SZ];

    const int tid = threadIdx.x;
    const bool isb = mask_is_byte(qmask);

    for (int i = tid; i < 1024; i += 256) {     // 1024 float4 slots per array
        int r = i >> 5, c4 = (i & 31) * 4;
        *(float4*)(qsL + r * 132 + c4) = *(const float4*)(qs + r * D_SZ + c4);
        *(float4*)(psL + r * 132 + c4) = *(const float4*)(ps + r * D_SZ + c4);
    }
    {                                           // token counts, 8 threads/row
        const int r = tid >> 3, j = tid & 7;
        int cnt = 0;
        if (isb) {
            const unsigned int* mm = (const unsigned int*)((const unsigned char*)qmask + r * T_SZ + j * 32);
            #pragma unroll
            for (int t = 0; t < 8; ++t) cnt += (int)((mm[t] * 0x01010101u) >> 24);
        } else {
            const int* mm = (const int*)qmask + r * T_SZ + j * 32;
            #pragma unroll
            for (int t = 0; t < 32; ++t) cnt += (mm[t] != 0);
        }
        cnt += __shfl_xor(cnt, 1);
        cnt += __shfl_xor(cnt, 2);
        cnt += __shfl_xor(cnt, 4);
        if (j == 0) tcnt[r] = (float)(cnt > 1 ? cnt : 1);
    }
    __syncthreads();

    for (int idx = tid; idx < B_SZ * B_SZ; idx += 256) {  // 4 (r,c) pairs/thread
        int r = idx >> 5, cc = idx & 31;
        float s = 0.f;
        #pragma unroll
        for (int i = 0; i < D_SZ; i += 4) {
            float4 a  = *(const float4*)(qsL + r  * 132 + i);
            float4 bb = *(const float4*)(psL + cc * 132 + i);
            s += a.x * bb.x + a.y * bb.y + a.z * bb.z + a.w * bb.w;
        }
        dense[r * 32 + cc] = s;
        late[r * 32 + cc]  = sraw[idx] / tcnt[r];
    }
    __syncthreads();

    // per-row softmax/CE/KL: 8 rows per pass, 32 lanes per row
    {
        const int cc = tid & 31;
        #pragma unroll
        for (int it = 0; it < 4; ++it) {
            const int r = (tid >> 5) + 8 * it;
            float xd = dense[r * 32 + cc] * TAU_INV;
            float xl = late[r * 32 + cc]  * TAU_INV;
            float md = xd, ml = xl;
            #pragma unroll
            for (int off = 16; off > 0; off >>= 1) {
                md = fmaxf(md, __shfl_xor(md, off));
                ml = fmaxf(ml, __shfl_xor(ml, off));
            }
            float sd = expf(xd - md), sl = expf(xl - ml);
            #pragma unroll
            for (int off = 16; off > 0; off >>= 1) {
                sd += __shfl_xor(sd, off);
                sl += __shfl_xor(sl, off);
            }
            float lsd = md + logf(sd);
            float lsl = ml + logf(sl);
            float pd = expf(xd - lsd);
            float pl = expf(xl - lsl);
            float klt = pd * logf((pd + 1e-8f) / (pl + 1e-8f));
            #pragma unroll
            for (int off = 16; off > 0; off >>= 1) klt += __shfl_xor(klt, off);
            if (cc == 0) rkA[r] = klt;
            if (cc == r) { rsA[r] = -(xd - lsd); rmA[r] = -(xl - lsl); }
        }
    }
    __syncthreads();

    if (tid < B_SZ) {
        float a = rsA[tid], bb = rmA[tid], c2 = rkA[tid];
        #pragma unroll
        for (int off = 16; off > 0; off >>= 1) {
            a  += __shfl_xor(a, off);
            bb += __shfl_xor(bb, off);
            c2 += __shfl_xor(c2, off);
        }
        if (tid == 0) {
            a *= (1.0f / B_SZ); bb *= (1.0f / B_SZ); c2 *= (1.0f / B_SZ);
            out[0] = a + bb + c2;  // total
            out[1] = a;            // single_loss
            out[2] = bb;           // multi_loss
            out[3] = c2;           // kl
        }
    }
}

// ---------------------------------------------------------------------------
extern "C" void kernel_launch(void* const* d_in, const int* in_sizes, int n_in,
                              void* d_out, int out_size, void* d_ws, size_t ws_size,
                              hipStream_t stream) {
    const float* qs    = (const float*)d_in[0];  // query_single [32,128]
    const float* ps    = (const float*)d_in[1];  // pos_single   [32,128]
    const float* qm3   = (const float*)d_in[2];  // query_multi  [32,256,128]
    const float* pm3   = (const float*)d_in[3];  // pos_multi    [32,256,128]
    const void*  qmask = d_in[4];                // q_mask [32,256]
    const void*  pmask = d_in[5];                // p_mask [32,256]
    float* out = (float*)d_out;

    const int NTOK = B_SZ * T_SZ * D_SZ;         // 1,048,576
    unsigned short* Qbf = (unsigned short*)d_ws;
    unsigned short* Pbf = Qbf + NTOK;
    float* sraw = (float*)(Pbf + NTOK);          // [1024]

    cvt_both<<<2048, 256, 0, stream>>>(qm3, pm3, Qbf, Pbf);
    late_sim<<<512, 512, 0, stream>>>(Qbf, Pbf, qmask, pmask, sraw);
    loss_final<<<1, 256, 0, stream>>>(qs, ps, sraw, qmask, out);
}